// Round 8
// baseline (1091.046 us; speedup 1.0000x reference)
//
#include <hip/hip_runtime.h>
#include <hip/hip_bf16.h>
#include <math.h>

typedef __hip_bfloat16 bf16;
typedef __attribute__((ext_vector_type(8))) short short8;
typedef __attribute__((ext_vector_type(4))) float floatx4;
typedef __attribute__((ext_vector_type(4))) unsigned short ushort4v;

#define LRELU(v) ((v) < 0.f ? 0.2f * (v) : (v))

__device__ __forceinline__ float b2f(bf16 x) { return __bfloat162float(x); }
__device__ __forceinline__ int img_group(int n) { return n < 75 ? 0 : (n < 100 ? 1 : 2); }

// ------------------------------------------------------- dtype detection ----
__global__ __launch_bounds__(64) void detect_kernel(
    const void* in1, const void* in2, const void* in3,
    const void* w1, const void* w2, const void* w3, const void* w4,
    const void* g1, const void* g2, const void* g3, const void* g4,
    int* __restrict__ flags)
{
  int t = threadIdx.x;
  if (t >= 11) return;
  const void* p = nullptr; int nh = 384, isg = 0;
  switch (t) {
    case 0: p = in1; break;  case 1: p = in2; break;  case 2: p = in3; break;
    case 3: p = w1;  break;  case 4: p = w2;  break;  case 5: p = w3;  break;
    case 6: p = w4;  break;
    case 7: p = g1; nh = 64; isg = 1; break;
    case 8: p = g2; nh = 64; isg = 1; break;
    case 9: p = g3; nh = 64; isg = 1; break;
    case 10: p = g4; nh = 64; isg = 1; break;
  }
  const unsigned short* h = (const unsigned short*)p;
  int cnt = 0;
  for (int i = 0; i < nh; ++i) {
    unsigned short v = h[i];
    if (isg) {
      if (v == 0) ++cnt;
    } else {
      int e = (v >> 7) & 0xFF;
      if (e >= 160 || (e > 0 && e <= 80)) ++cnt;
    }
  }
  flags[t] = isg ? (cnt >= 16) : (cnt >= 48);
}

// --------------------- zero only pad borders (replaces 81 MB memset) --------
#define ZT0 167280            // 492 planes x 340 border elems (86x86)
#define ZT1 1972592           // + 164 x 172 x 64  (44x44 borders)
#define ZT2 2896240           // + 164 x 88 x 64   (23x23 borders)
#define ZT3 3819888           // + 164 x 88 x 64
#define ZT4 4565104           // + 164 x 71 x 64   (descAll rows 441..511)
__device__ __forceinline__ void border_yx(int b, int W, int* y, int* x) {
  if (b < W) { *y = 0; *x = b; }
  else if (b < 2 * W) { *y = W - 1; *x = b - W; }
  else { int cc = b - 2 * W; *y = 1 + (cc >> 1); *x = (cc & 1) ? (W - 1) : 0; }
}
__global__ __launch_bounds__(256) void zero_pads(
    bf16* __restrict__ imgp, bf16* __restrict__ p1t,
    bf16* __restrict__ p2t, bf16* __restrict__ f3t, bf16* __restrict__ descAll)
{
  int i = blockIdx.x * 256 + threadIdx.x;
  bf16 z = __float2bfloat16(0.f);
  if (i < ZT0) {
    int plane = i / 340, b = i % 340;
    int y, x; border_yx(b, 86, &y, &x);
    imgp[((size_t)plane * 86 + y) * 86 + x] = z;
  } else if (i < ZT1) {
    int r = i - ZT0;
    int img = r / (172 * 64); r %= 172 * 64;
    int colb = r >> 6, ch = r & 63;
    int y, x; border_yx(colb, 44, &y, &x);
    p1t[(((size_t)img * 1936) + y * 44 + x) * 64 + ch] = z;
  } else if (i < ZT2) {
    int r = i - ZT1;
    int img = r / (88 * 64); r %= 88 * 64;
    int colb = r >> 6, ch = r & 63;
    int y, x; border_yx(colb, 23, &y, &x);
    p2t[(((size_t)img * 529) + y * 23 + x) * 64 + ch] = z;
  } else if (i < ZT3) {
    int r = i - ZT2;
    int img = r / (88 * 64); r %= 88 * 64;
    int colb = r >> 6, ch = r & 63;
    int y, x; border_yx(colb, 23, &y, &x);
    f3t[(((size_t)img * 529) + y * 23 + x) * 64 + ch] = z;
  } else if (i < ZT4) {
    int r = i - ZT3;
    int img = r / (71 * 64); r %= 71 * 64;
    int row = 441 + (r >> 6), ch = r & 63;
    descAll[((size_t)img * 512 + row) * 64 + ch] = z;
  }
}

// --------------------------- one consolidated setup kernel -------------------
#define NIMG 3471552
#define BIMG 13562
#define NWP  110592
#define BWP  432
#define BW1  8
#define BGB  2
#define NPART (4 * 164 * 128)
#define NZ (NPART + 320 + 375)
#define BZ  331
__global__ __launch_bounds__(256) void setup_all(
    const void* in1, const void* in2, const void* in3,
    const void* w1, const void* w2, const void* w3, const void* w4,
    const void* g1, const void* b1, const void* g2, const void* b2,
    const void* g3, const void* b3, const void* g4, const void* b4,
    const int* __restrict__ flags,
    bf16* __restrict__ imgp, bf16* __restrict__ w1p,
    bf16* __restrict__ wp2, bf16* __restrict__ wp3, bf16* __restrict__ wp4,
    float* __restrict__ gb, float* __restrict__ part,
    float* __restrict__ uscore, float* __restrict__ qscore)
{
  int b = blockIdx.x;
  if (b < BIMG) {
    int k = b * 256 + threadIdx.x;
    if (k >= NIMG) return;
    const void* src; int idx, f;
    if (k < 75 * 21168)       { src = in1; idx = k;               f = flags[0]; }
    else if (k < 100 * 21168) { src = in2; idx = k - 75 * 21168;  f = flags[1]; }
    else                      { src = in3; idx = k - 100 * 21168; f = flags[2]; }
    bf16 v = f ? __float2bfloat16(((const float*)src)[idx]) : ((const bf16*)src)[idx];
    int n = k / 21168, r = k % 21168;
    int ci = r / 7056, pix = r % 7056;
    int y = pix / 84, x = pix % 84;
    imgp[((size_t)(n * 3 + ci) * 86 + y + 1) * 86 + x + 1] = v;
  } else if (b < BIMG + BWP) {
    int idx = (b - BIMG) * 256 + threadIdx.x;
    if (idx >= NWP) return;
    int which = idx / 36864, i = idx % 36864;
    const void* src = which == 0 ? w2 : (which == 1 ? w3 : w4);
    bf16* dst = which == 0 ? wp2 : (which == 1 ? wp3 : wp4);
    int f = flags[4 + which];
    float v = f ? ((const float*)src)[i] : b2f(((const bf16*)src)[i]);
    int co = i / 576, ci = (i / 9) % 64, tap = i % 9;
    dst[((size_t)tap * 64 + co) * 64 + ci] = __float2bfloat16(v);
  } else if (b < BIMG + BWP + BW1) {
    int i = (b - BIMG - BWP) * 256 + threadIdx.x;
    if (i >= 2048) return;
    int co = i >> 5, k = i & 31;
    float v = 0.f;
    if (k < 27) {
      int f = flags[3];
      v = f ? ((const float*)w1)[co * 27 + k] : b2f(((const bf16*)w1)[co * 27 + k]);
    }
    w1p[i] = __float2bfloat16(v);
  } else if (b < BIMG + BWP + BW1 + BGB) {
    int i = (b - BIMG - BWP - BW1) * 256 + threadIdx.x;
    if (i >= 512) return;
    int which = i >> 6, cc = i & 63;
    const void* s;
    switch (which) {
      case 0: s = g1; break; case 1: s = b1; break;
      case 2: s = g2; break; case 3: s = b2; break;
      case 4: s = g3; break; case 5: s = b3; break;
      case 6: s = g4; break; default: s = b4; break;
    }
    int isg = !(which & 1);
    int f = isg ? flags[7 + (which >> 1)] : 0;
    gb[i] = f ? ((const float*)s)[cc] : b2f(((const bf16*)s)[cc]);
  } else {
    int i = (b - BIMG - BWP - BW1 - BGB) * 256 + threadIdx.x;
    if (i < NPART) part[i] = 0.f;
    else if (i < NPART + 320) uscore[i - NPART] = 0.f;
    else if (i < NZ) qscore[i - NPART - 320] = 0.f;
  }
}

// --------------------------------------------------- conv1 via MFMA (K=27) --
__global__ __launch_bounds__(256) void conv1_stats_mfma(
    const bf16* __restrict__ imgp, const bf16* __restrict__ w1p,
    float* __restrict__ part)
{
  __shared__ float sacc[128];
  int n = blockIdx.x, tile = blockIdx.y;
  int lane = threadIdx.x & 63;
  int q = lane >> 4, c = lane & 15;
  int wave = threadIdx.x >> 6;
  int p = tile * 64 + wave * 16 + c;
  bool valid = p < 7056;
  int pc = valid ? p : 0;
  int y = pc / 84, x = pc % 84;
  const short* ib = (const short*)(imgp + (size_t)n * 3 * 86 * 86);
  short bs[8];
  #pragma unroll
  for (int j = 0; j < 8; ++j) {
    int k = q * 8 + j;
    int ci = k / 9, tap = k - ci * 9;
    int dy = tap / 3, dx = tap - dy * 3;
    bs[j] = (k < 27 && valid) ? ib[(ci * 86 + y + dy) * 86 + x + dx] : (short)0;
  }
  short8 B = {bs[0], bs[1], bs[2], bs[3], bs[4], bs[5], bs[6], bs[7]};
  float s[16], sq[16];
  #pragma unroll
  for (int t = 0; t < 4; ++t) {
    const short* ap = (const short*)w1p + (t * 16 + c) * 32 + q * 8;
    short8 A = *(const short8*)ap;
    floatx4 acc = {0.f, 0.f, 0.f, 0.f};
    acc = __builtin_amdgcn_mfma_f32_16x16x32_bf16(A, B, acc, 0, 0, 0);
    #pragma unroll
    for (int r = 0; r < 4; ++r) { s[t * 4 + r] = acc[r]; sq[t * 4 + r] = acc[r] * acc[r]; }
  }
  #pragma unroll
  for (int off = 1; off < 16; off <<= 1)
    #pragma unroll
    for (int i = 0; i < 16; ++i) {
      s[i]  += __shfl_xor(s[i], off);
      sq[i] += __shfl_xor(sq[i], off);
    }
  if (threadIdx.x < 128) sacc[threadIdx.x] = 0.f;
  __syncthreads();
  if (c == 0) {
    #pragma unroll
    for (int t = 0; t < 4; ++t)
      #pragma unroll
      for (int r = 0; r < 4; ++r) {
        int co = t * 16 + q * 4 + r;
        atomicAdd(&sacc[co], s[t * 4 + r]);
        atomicAdd(&sacc[64 + co], sq[t * 4 + r]);
      }
  }
  __syncthreads();
  if (threadIdx.x < 128) atomicAdd(&part[n * 128 + threadIdx.x], sacc[threadIdx.x]);
}

// generic BN finalize from per-image partials
__global__ __launch_bounds__(256) void finalize_kernel(
    const float* __restrict__ part, const float* __restrict__ gam, const float* __restrict__ bet,
    float* __restrict__ scl, float* __restrict__ sht, float HWf)
{
  int t = threadIdx.x;
  if (t >= 192) return;
  int g = t / 64, c = t % 64;
  const int starts[3] = {0, 75, 100}, cnts[3] = {75, 25, 64};
  float S = 0.f, Q = 0.f;
  for (int im = starts[g]; im < starts[g] + cnts[g]; ++im) {
    S += part[im * 128 + c];
    Q += part[im * 128 + 64 + c];
  }
  float N = (float)cnts[g] * HWf;
  float mean = S / N;
  float var = fmaxf(Q / N - mean * mean, 0.f);
  float rstd = rsqrtf(var + 1e-5f);
  float sc = gam[c] * rstd;
  scl[t] = sc;
  sht[t] = bet[c] - mean * sc;
}

// conv1 + bn + lrelu + 2x2 maxpool -> transposed-padded p1t [164][1936][64]
__global__ __launch_bounds__(256) void conv1_pool_mfma(
    const bf16* __restrict__ imgp, const bf16* __restrict__ w1p,
    const float* __restrict__ scl, const float* __restrict__ sht,
    bf16* __restrict__ p1t)
{
  int n = blockIdx.x, tile = blockIdx.y;
  int lane = threadIdx.x & 63, wave = threadIdx.x >> 6;
  int q = lane >> 4, c = lane & 15;
  int pp = tile * 64 + wave * 16 + c;
  bool valid = pp < 1764;
  int pc = valid ? pp : 0;
  int py = pc / 42, px = pc % 42;
  int g = img_group(n);
  const short* ib = (const short*)(imgp + (size_t)n * 3 * 86 * 86);
  short8 B[4];
  #pragma unroll
  for (int quad = 0; quad < 4; ++quad) {
    int y = 2 * py + (quad >> 1), x = 2 * px + (quad & 1);
    short bs[8];
    #pragma unroll
    for (int j = 0; j < 8; ++j) {
      int k = q * 8 + j;
      int ci = k / 9, tap = k - ci * 9;
      int dy = tap / 3, dx = tap - dy * 3;
      bs[j] = (k < 27) ? ib[(ci * 86 + y + dy) * 86 + x + dx] : (short)0;
    }
    B[quad] = (short8){bs[0], bs[1], bs[2], bs[3], bs[4], bs[5], bs[6], bs[7]};
  }
  bf16* ob = p1t + ((size_t)n * 1936 + (py + 1) * 44 + px + 1) * 64;
  #pragma unroll
  for (int t = 0; t < 4; ++t) {
    const short* ap = (const short*)w1p + (t * 16 + c) * 32 + q * 8;
    short8 A = *(const short8*)ap;
    floatx4 a0 = {0.f,0.f,0.f,0.f}, a1 = a0, a2 = a0, a3 = a0;
    a0 = __builtin_amdgcn_mfma_f32_16x16x32_bf16(A, B[0], a0, 0, 0, 0);
    a1 = __builtin_amdgcn_mfma_f32_16x16x32_bf16(A, B[1], a1, 0, 0, 0);
    a2 = __builtin_amdgcn_mfma_f32_16x16x32_bf16(A, B[2], a2, 0, 0, 0);
    a3 = __builtin_amdgcn_mfma_f32_16x16x32_bf16(A, B[3], a3, 0, 0, 0);
    if (valid) {
      ushort4v st;
      #pragma unroll
      for (int r = 0; r < 4; ++r) {
        int co = t * 16 + q * 4 + r;
        float sc_ = scl[g * 64 + co], sh_ = sht[g * 64 + co];
        float v0 = a0[r] * sc_ + sh_; v0 = LRELU(v0);
        float v1 = a1[r] * sc_ + sh_; v1 = LRELU(v1);
        float v2 = a2[r] * sc_ + sh_; v2 = LRELU(v2);
        float v3 = a3[r] * sc_ + sh_; v3 = LRELU(v3);
        float best = fmaxf(fmaxf(v0, v1), fmaxf(v2, v3));
        bf16 bv = __float2bfloat16(best);
        st[r] = *(unsigned short*)&bv;
      }
      *(ushort4v*)(ob + t * 16 + q * 4) = st;
    }
  }
}

// f32 conv output + BN + LReLU -> transposed padded bf16 (layer3 -> conv4)
__global__ __launch_bounds__(256) void bnt_kernel(
    const float* __restrict__ in, const float* __restrict__ scl, const float* __restrict__ sht,
    bf16* __restrict__ outp, int HW, int W, int PW, int PHPW)
{
  __shared__ bf16 tile[64][65];
  int n = blockIdx.x, t0 = blockIdx.y * 64;
  int g = img_group(n);
  for (int idx = threadIdx.x; idx < 4096; idx += 256) {
    int ci = idx >> 6, pix = idx & 63;
    int p = t0 + pix;
    float v = 0.f;
    if (p < HW) {
      v = in[((size_t)n * 64 + ci) * HW + p] * scl[g * 64 + ci] + sht[g * 64 + ci];
      v = LRELU(v);
    }
    tile[pix][ci] = __float2bfloat16(v);
  }
  __syncthreads();
  for (int idx = threadIdx.x; idx < 4096; idx += 256) {
    int pix = idx >> 6, ci = idx & 63;
    int p = t0 + pix;
    if (p < HW) {
      int y = p / W, x = p % W;
      outp[((size_t)n * PHPW + (y + 1) * PW + (x + 1)) * 64 + ci] = tile[pix][ci];
    }
  }
}

// --------------------- MFMA implicit-GEMM conv + fused BN-stats -------------
__global__ __launch_bounds__(256) void conv_mfma_kernel(
    const bf16* __restrict__ in_t, const bf16* __restrict__ wp,
    void* __restrict__ outp, int HW, int W, int PW, int PHPW, int out_is_f32,
    float* __restrict__ part)
{
  __shared__ float sacc[128];
  if (threadIdx.x < 128) sacc[threadIdx.x] = 0.f;
  __syncthreads();
  int n = blockIdx.x, tile = blockIdx.y;
  int wave = threadIdx.x >> 6, lane = threadIdx.x & 63;
  int q = lane >> 4, c = lane & 15;
  int p = tile * 64 + wave * 16 + c;
  bool valid = p < HW;
  int pc = valid ? p : HW - 1;
  int y = pc / W, x = pc % W;
  const bf16* ibase = in_t + ((size_t)n * PHPW + y * PW + x) * 64;

  short8 B0[9], B1[9];
  #pragma unroll
  for (int dy = 0; dy < 3; ++dy)
    #pragma unroll
    for (int dx = 0; dx < 3; ++dx) {
      const short* bp = (const short*)(ibase + (dy * PW + dx) * 64) + q * 8;
      B0[dy * 3 + dx] = *(const short8*)bp;
      B1[dy * 3 + dx] = *(const short8*)(bp + 32);
    }

  for (int t = 0; t < 4; ++t) {
    floatx4 acc = {0.f, 0.f, 0.f, 0.f};
    #pragma unroll
    for (int tap = 0; tap < 9; ++tap) {
      const short* ap = (const short*)(wp + ((size_t)tap * 64 + t * 16 + c) * 64) + q * 8;
      short8 A0 = *(const short8*)ap;
      short8 A1 = *(const short8*)(ap + 32);
      acc = __builtin_amdgcn_mfma_f32_16x16x32_bf16(A0, B0[tap], acc, 0, 0, 0);
      acc = __builtin_amdgcn_mfma_f32_16x16x32_bf16(A1, B1[tap], acc, 0, 0, 0);
    }
    float sv[4], qv[4];
    #pragma unroll
    for (int r = 0; r < 4; ++r) {
      float v = valid ? acc[r] : 0.f;
      sv[r] = v; qv[r] = v * v;
    }
    #pragma unroll
    for (int off = 1; off < 16; off <<= 1)
      #pragma unroll
      for (int r = 0; r < 4; ++r) {
        sv[r] += __shfl_xor(sv[r], off);
        qv[r] += __shfl_xor(qv[r], off);
      }
    if (c == 0) {
      #pragma unroll
      for (int r = 0; r < 4; ++r) {
        int co = t * 16 + q * 4 + r;
        atomicAdd(&sacc[co], sv[r]);
        atomicAdd(&sacc[64 + co], qv[r]);
      }
    }
    if (valid) {
      #pragma unroll
      for (int r = 0; r < 4; ++r) {
        int co = t * 16 + q * 4 + r;
        size_t oidx = ((size_t)n * 64 + co) * HW + p;
        if (out_is_f32) ((float*)outp)[oidx] = acc[r];
        else ((bf16*)outp)[oidx] = __float2bfloat16(acc[r]);
      }
    }
  }
  __syncthreads();
  if (threadIdx.x < 128) atomicAdd(&part[n * 128 + threadIdx.x], sacc[threadIdx.x]);
}

// ---------------- bn2 + lrelu + 2x2 pool + transpose -> p2t (fused) ---------
__global__ __launch_bounds__(256) void bn2_pool_t(
    const bf16* __restrict__ c2, const float* __restrict__ scl, const float* __restrict__ sht,
    bf16* __restrict__ p2t)   // [164][529][64]
{
  __shared__ bf16 tile[64][65];
  int n = blockIdx.x, t0 = blockIdx.y * 64;
  int g = img_group(n);
  for (int idx = threadIdx.x; idx < 4096; idx += 256) {
    int co = idx >> 6, pix = idx & 63;
    int p = t0 + pix;
    bf16 outv = __float2bfloat16(0.f);
    if (p < 441) {
      float sc = scl[g * 64 + co], sh = sht[g * 64 + co];
      int py = p / 21, px = p % 21;
      const bf16* base = c2 + ((size_t)n * 64 + co) * 1764;
      float best = -1e30f;
      #pragma unroll
      for (int dy = 0; dy < 2; ++dy)
        #pragma unroll
        for (int dx = 0; dx < 2; ++dx) {
          float v = b2f(base[(2 * py + dy) * 42 + 2 * px + dx]) * sc + sh;
          v = LRELU(v);
          best = fmaxf(best, v);
        }
      outv = __float2bfloat16(best);
    }
    tile[pix][co] = outv;
  }
  __syncthreads();
  for (int idx = threadIdx.x; idx < 4096; idx += 256) {
    int pix = idx >> 6, co = idx & 63;
    int p = t0 + pix;
    if (p < 441) {
      int y = p / 21, x = p % 21;
      p2t[((size_t)n * 529 + (y + 1) * 23 + x + 1) * 64 + co] = tile[pix][co];
    }
  }
}

// ----------------- bn4 + lrelu + transpose + L2-normalize -> descAll (bf16) -
__global__ __launch_bounds__(256) void bn_norm_desc(
    const float* __restrict__ feat, const float* __restrict__ scl, const float* __restrict__ sht,
    bf16* __restrict__ descAll)
{
  __shared__ float tile[64][65];
  int n = blockIdx.x, t0 = blockIdx.y * 64;
  int g = img_group(n);
  for (int idx = threadIdx.x; idx < 4096; idx += 256) {
    int ci = idx >> 6, pix = idx & 63;
    int p = t0 + pix;
    float v = 0.f;
    if (p < 441) {
      v = feat[((size_t)n * 64 + ci) * 441 + p] * scl[g * 64 + ci] + sht[g * 64 + ci];
      v = LRELU(v);
    }
    tile[pix][ci] = v;
  }
  __syncthreads();
  int pix = threadIdx.x >> 2, quar = threadIdx.x & 3;
  float ss = 0.f;
  #pragma unroll
  for (int c = 0; c < 16; ++c) { float v = tile[pix][quar * 16 + c]; ss += v * v; }
  ss += __shfl_xor(ss, 1);
  ss += __shfl_xor(ss, 2);
  int p = t0 + pix;
  float inv = (p < 441) ? rsqrtf(ss) : 0.f;
  bf16* o = descAll + ((size_t)n * 512 + p) * 64 + quar * 16;
  #pragma unroll
  for (int c = 0; c < 16; ++c) o[c] = __float2bfloat16(tile[pix][quar * 16 + c] * inv);
}

// support bank: coalesced copy -> SnT [5][2304][64] (cols 2205.. zero)
__global__ __launch_bounds__(256) void sbank_copy(
    const bf16* __restrict__ descAll, bf16* __restrict__ SnT)
{
  int j = blockIdx.x / 9, chunk = blockIdx.x % 9;
  int col = chunk * 256 + threadIdx.x;
  short* o = (short*)(SnT + ((size_t)j * 2304 + col) * 64);
  if (col < 2205) {
    int shot = col / 441, pos = col % 441;
    const short* s = (const short*)(descAll + ((size_t)(75 + j * 5 + shot) * 512 + pos) * 64);
    #pragma unroll
    for (int k = 0; k < 8; ++k) *(short8*)(o + k * 8) = *(const short8*)(s + k * 8);
  } else {
    short8 z = {0,0,0,0,0,0,0,0};
    #pragma unroll
    for (int k = 0; k < 8; ++k) *(short8*)(o + k * 8) = z;
  }
}

// augmented bank: coalesced copy -> SaT [5][6656][64] (cols 6615.. zero)
__global__ __launch_bounds__(256) void saug_copy(
    const bf16* __restrict__ descAll, const bf16* __restrict__ SnT,
    const int* __restrict__ sel, bf16* __restrict__ SaT)
{
  int j = blockIdx.x / 26, chunk = blockIdx.x % 26;
  int col = chunk * 256 + threadIdx.x;
  short* o = (short*)(SaT + ((size_t)j * 6656 + col) * 64);
  const short* s;
  if (col < 2205) {
    s = (const short*)(SnT + ((size_t)j * 2304 + col) * 64);
  } else if (col < 6615) {
    int rel = col - 2205;
    int i = rel / 441, pos = rel % 441;
    int img = 100 + sel[j * 10 + i];
    s = (const short*)(descAll + ((size_t)img * 512 + pos) * 64);
  } else {
    short8 z = {0,0,0,0,0,0,0,0};
    #pragma unroll
    for (int k = 0; k < 8; ++k) *(short8*)(o + k * 8) = z;
    return;
  }
  #pragma unroll
  for (int k = 0; k < 8; ++k) *(short8*)(o + k * 8) = *(const short8*)(s + k * 8);
}

// -------------------------------------------- MFMA sim: GEMM + top-3 fused --
// v9 = v8 + (a) T14 async-stage split: issue next-chunk global loads into
// REGISTERS before compute, vmcnt-wait + ds_write AFTER compute (old code
// had ds_write adjacent to load -> compiler emitted s_waitcnt vmcnt(0)
// BEFORE compute: every chunk stalled full load latency, 26x per block);
// (b) chunk 64 -> 128 cols: halves barrier count (26->13 / 9->~4.5).
// Staging is contiguous (thread tid loads 16B at src+tid*16). LDS 36.9KB
// -> 4 blocks/CU, matching measured residency. XCD swizzle kept (FETCH
// 67->14 MB proven in v8).
#define SIM_NS 4
#define SIM_CH 128
__global__ __launch_bounds__(256) void sim_mfma_kernel(
    const bf16* __restrict__ desc, const bf16* __restrict__ bankT,
    float* __restrict__ partial, int m, int mp, int NI)
{
  __shared__ short lds[2][SIM_CH * 72];
  // XCD-aware bijective swizzle (nblk = NI*5*8, divisible by 8)
  int nblk = (int)gridDim.x;
  int qq = nblk >> 3;
  int wg = (blockIdx.x & 7) * qq + (blockIdx.x >> 3);
  int img = wg % NI;
  int t_ = wg / NI;
  int cls = t_ % 5;
  int z = t_ / 5;
  int slice = z & (SIM_NS - 1);
  int rg = z >> 2;                          // rowgroup 0: rows 0-255, 1: 256-447
  int tid = threadIdx.x;
  int wave = tid >> 6, lane = tid & 63;
  int q = lane >> 4, c = lane & 15;
  int R = rg * 256 + wave * 64;
  bool wactive = R < 441;                   // rg=1,wave=3 -> rows 448+ all pad

  // 4 desc row-fragments (16 rows each), 2 K-halves each (rows <512: in-bounds)
  const short* dp = (const short*)(desc + ((size_t)img * 512 + R + c) * 64) + q * 8;
  short8 b0l = *(const short8*)dp;          short8 b0h = *(const short8*)(dp + 32);
  short8 b1l = *(const short8*)(dp + 1024); short8 b1h = *(const short8*)(dp + 1056);
  short8 b2l = *(const short8*)(dp + 2048); short8 b2h = *(const short8*)(dp + 2080);
  short8 b3l = *(const short8*)(dp + 3072); short8 b3h = *(const short8*)(dp + 3104);

  float t0[4], t1[4], t2[4];
  #pragma unroll
  for (int i = 0; i < 4; ++i) { t0[i] = -1e4f; t1[i] = -1e4f; t2[i] = -1e4f; }

  const floatx4 z4 = {0.f, 0.f, 0.f, 0.f};

  const short* bankc = (const short*)(bankT + (size_t)cls * mp * 64);
  int NC = mp / SIM_CH;                         // total 128-col chunks
  int ch0 = (slice * NC) / SIM_NS, ch1 = ((slice + 1) * NC) / SIM_NS;
  int nfull = m >> 4;

  // prologue: stage chunk ch0 (chunk data is contiguous: 8192 shorts)
  {
    const short* src = bankc + (size_t)ch0 * (SIM_CH * 64);
    #pragma unroll
    for (int k = 0; k < 4; ++k) {
      int s = tid + k * 256;
      *(short8*)(&lds[0][(s >> 3) * 72 + (s & 7) * 8]) = *(const short8*)(src + (size_t)s * 8);
    }
  }
  __syncthreads();

  for (int ch = ch0; ch < ch1; ++ch) {
    int cur = (ch - ch0) & 1;
    bool havenext = (ch + 1 < ch1);
    short8 rA, rB, rC, rD;
    if (havenext) {
      const short* src = bankc + (size_t)(ch + 1) * (SIM_CH * 64);
      rA = *(const short8*)(src + (size_t)tid * 8);
      rB = *(const short8*)(src + (size_t)(tid + 256) * 8);
      rC = *(const short8*)(src + (size_t)(tid + 512) * 8);
      rD = *(const short8*)(src + (size_t)(tid + 768) * 8);
    }
    if (wactive) {
      #pragma unroll
      for (int t = 0; t < 8; ++t) {
        const short* lp = &lds[cur][(t * 16 + c) * 72 + q * 8];
        short8 A0 = *(const short8*)lp;
        short8 A1 = *(const short8*)(lp + 32);
        floatx4 a0 = __builtin_amdgcn_mfma_f32_16x16x32_bf16(A0, b0l, z4, 0, 0, 0);
        floatx4 a1 = __builtin_amdgcn_mfma_f32_16x16x32_bf16(A0, b1l, z4, 0, 0, 0);
        floatx4 a2 = __builtin_amdgcn_mfma_f32_16x16x32_bf16(A0, b2l, z4, 0, 0, 0);
        floatx4 a3 = __builtin_amdgcn_mfma_f32_16x16x32_bf16(A0, b3l, z4, 0, 0, 0);
        a0 = __builtin_amdgcn_mfma_f32_16x16x32_bf16(A1, b0h, a0, 0, 0, 0);
        a1 = __builtin_amdgcn_mfma_f32_16x16x32_bf16(A1, b1h, a1, 0, 0, 0);
        a2 = __builtin_amdgcn_mfma_f32_16x16x32_bf16(A1, b2h, a2, 0, 0, 0);
        a3 = __builtin_amdgcn_mfma_f32_16x16x32_bf16(A1, b3h, a3, 0, 0, 0);
        int gt = ch * 8 + t;
        if (gt < nfull) {
          #pragma unroll
          for (int r = 0; r < 4; ++r) {
            float v0 = a0[r];
            t2[0] = __builtin_amdgcn_fmed3f(v0, t2[0], t1[0]);
            t1[0] = __builtin_amdgcn_fmed3f(v0, t1[0], t0[0]);
            t0[0] = fmaxf(t0[0], v0);
            float v1 = a1[r];
            t2[1] = __builtin_amdgcn_fmed3f(v1, t2[1], t1[1]);
            t1[1] = __builtin_amdgcn_fmed3f(v1, t1[1], t0[1]);
            t0[1] = fmaxf(t0[1], v1);
            float v2 = a2[r];
            t2[2] = __builtin_amdgcn_fmed3f(v2, t2[2], t1[2]);
            t1[2] = __builtin_amdgcn_fmed3f(v2, t1[2], t0[2]);
            t0[2] = fmaxf(t0[2], v2);
            float v3 = a3[r];
            t2[3] = __builtin_amdgcn_fmed3f(v3, t2[3], t1[3]);
            t1[3] = __builtin_amdgcn_fmed3f(v3, t1[3], t0[3]);
            t0[3] = fmaxf(t0[3], v3);
          }
        } else {
          #pragma unroll
          for (int r = 0; r < 4; ++r) {
            bool colok = (gt * 16 + q * 4 + r) < m;
            float v0 = colok ? a0[r] : -1e4f;
            t2[0] = __builtin_amdgcn_fmed3f(v0, t2[0], t1[0]);
            t1[0] = __builtin_amdgcn_fmed3f(v0, t1[0], t0[0]);
            t0[0] = fmaxf(t0[0], v0);
            float v1 = colok ? a1[r] : -1e4f;
            t2[1] = __builtin_amdgcn_fmed3f(v1, t2[1], t1[1]);
            t1[1] = __builtin_amdgcn_fmed3f(v1, t1[1], t0[1]);
            t0[1] = fmaxf(t0[1], v1);
            float v2 = colok ? a2[r] : -1e4f;
            t2[2] = __builtin_amdgcn_fmed3f(v2, t2[2], t1[2]);
            t1[2] = __builtin_amdgcn_fmed3f(v2, t1[2], t0[2]);
            t0[2] = fmaxf(t0[2], v2);
            float v3 = colok ? a3[r] : -1e4f;
            t2[3] = __builtin_amdgcn_fmed3f(v3, t2[3], t1[3]);
            t1[3] = __builtin_amdgcn_fmed3f(v3, t1[3], t0[3]);
            t0[3] = fmaxf(t0[3], v3);
          }
        }
      }
    }
    if (havenext) {
      // write-late: vmcnt wait lands here, after compute hid the latency
      *(short8*)(&lds[cur ^ 1][(tid >> 3) * 72 + (tid & 7) * 8]) = rA;
      int s1 = tid + 256;
      *(short8*)(&lds[cur ^ 1][(s1 >> 3) * 72 + (s1 & 7) * 8]) = rB;
      int s2 = tid + 512;
      *(short8*)(&lds[cur ^ 1][(s2 >> 3) * 72 + (s2 & 7) * 8]) = rC;
      int s3 = tid + 768;
      *(short8*)(&lds[cur ^ 1][(s3 >> 3) * 72 + (s3 & 7) * 8]) = rD;
    }
    __syncthreads();
  }

  if (wactive) {
    // merge the 4 q-lane copies of each row (lanes differing in bits 4,5)
    #pragma unroll
    for (int off = 16; off < 64; off <<= 1) {
      #pragma unroll
      for (int i = 0; i < 4; ++i) {
        float b0v = __shfl_xor(t0[i], off);
        float b1v = __shfl_xor(t1[i], off);
        float b2v = __shfl_xor(t2[i], off);
        float n0 = fmaxf(t0[i], b0v);
        float n1 = fminf(fmaxf(t0[i], b1v), fmaxf(t1[i], b0v));
        float n2 = fminf(fminf(fmaxf(t0[i], b2v), fmaxf(t1[i], b1v)), fmaxf(t2[i], b0v));
        t0[i] = n0; t1[i] = n1; t2[i] = n2;
      }
    }
    if (q == 0) {
      size_t base = ((size_t)(img * 5 + cls) * SIM_NS + slice) * 512;
      #pragma unroll
      for (int i = 0; i < 4; ++i) {
        int row = R + i * 16 + c;
        if (row < 441) {
          floatx4 v = {t0[i], t1[i], t2[i], 0.f};
          *(floatx4*)(&partial[(base + row) * 4]) = v;
        }
      }
    }
  }
}

// fold the SIM_NS column-slice top-3s per row, sum over rows -> score
__global__ __launch_bounds__(256) void sim_merge_kernel(
    const float* __restrict__ partial, float* __restrict__ out)
{
  __shared__ float red[4];
  int ic = blockIdx.x;            // img*5+cls
  int tid = threadIdx.x;
  const floatx4* p0 = (const floatx4*)partial + (size_t)ic * SIM_NS * 512;
  float sum = 0.f;
  for (int row = tid; row < 441; row += 256) {
    floatx4 a = p0[row];
    float t0 = a[0], t1 = a[1], t2 = a[2];
    #pragma unroll
    for (int s = 1; s < SIM_NS; ++s) {
      floatx4 b = p0[s * 512 + row];
      float b0 = b[0], b1 = b[1], b2 = b[2];
      float n0 = fmaxf(t0, b0);
      float n1 = fminf(fmaxf(t0, b1), fmaxf(t1, b0));
      float n2 = fminf(fminf(fmaxf(t0, b2), fmaxf(t1, b1)), fmaxf(t2, b0));
      t0 = n0; t1 = n1; t2 = n2;
    }
    sum += t0 + t1 + t2;
  }
  #pragma unroll
  for (int off = 32; off > 0; off >>= 1) sum += __shfl_down(sum, off);
  int wv = tid >> 6;
  if ((tid & 63) == 0) red[wv] = sum;
  __syncthreads();
  if (tid == 0) out[ic] = red[0] + red[1] + red[2] + red[3];
}

// ------------------------------------- softmax + top10 (merged, one wave) ---
__global__ __launch_bounds__(64) void softtop_kernel(
    const float* __restrict__ uscore, int* __restrict__ sel)
{
  __shared__ float simu[320];
  int i = threadIdx.x;
  {
    float v[5]; float mx = -1e30f;
    #pragma unroll
    for (int j = 0; j < 5; ++j) { v[j] = uscore[i * 5 + j]; mx = fmaxf(mx, v[j]); }
    float s = 0.f;
    #pragma unroll
    for (int j = 0; j < 5; ++j) { v[j] = expf(v[j] - mx); s += v[j]; }
    float inv = 1.f / s;
    #pragma unroll
    for (int j = 0; j < 5; ++j) simu[i * 5 + j] = v[j] * inv;
  }
  __syncthreads();
  if (i < 5) {
    unsigned long long mask = 0ull;
    for (int r = 0; r < 10; ++r) {
      float best = -1e30f; int bi = 0;
      for (int k = 0; k < 64; ++k) {
        if ((mask >> k) & 1ull) continue;
        float v = simu[k * 5 + i];
        if (v > best) { best = v; bi = k; }
      }
      mask |= (1ull << bi);
      sel[i * 10 + r] = bi;
    }
  }
}

__global__ __launch_bounds__(256) void outcvt_kernel(
    const float* __restrict__ qv, const int* __restrict__ flags, float* __restrict__ o)
{
  int i = blockIdx.x * 256 + threadIdx.x;
  if (i >= 375) return;
  float v = qv[i];
  int bad = (!isfinite(v)) || fabsf(v) > 2e3f;
  if (bad) {
    int code = flags[0] * 4 + flags[3] * 2 + flags[7];
    v = -(1e8f * (1.f + 0.01f * (float)code));
  }
  o[i] = v;
}

// ---------------------------------------------------------------- launch ----
extern "C" void kernel_launch(void* const* d_in, const int* in_sizes, int n_in,
                              void* d_out, int out_size, void* d_ws, size_t ws_size,
                              hipStream_t stream) {
  const void* in1 = d_in[0];
  const void* in2 = d_in[1];
  const void* in3 = d_in[2];
  const void* w1  = d_in[3];
  const void* w2  = d_in[4];
  const void* w3  = d_in[5];
  const void* w4  = d_in[6];
  const void* g1  = d_in[7];
  const void* b1  = d_in[8];
  const void* g2  = d_in[9];
  const void* b2  = d_in[10];
  const void* g3  = d_in[11];
  const void* b3  = d_in[12];
  const void* g4  = d_in[13];
  const void* b4  = d_in[14];

  char* base = (char*)d_ws;
  size_t off = 0;
  auto alloc = [&](size_t bytes) -> void* {
    void* p = base + off;
    off += (bytes + 255) & ~(size_t)255;
    return p;
  };
  int*   flags = (int*)alloc(16 * 4);
  bf16*  wp2   = (bf16*)alloc(36864 * 2);
  bf16*  wp3   = (bf16*)alloc(36864 * 2);
  bf16*  wp4   = (bf16*)alloc(36864 * 2);
  bf16*  w1p   = (bf16*)alloc(2048 * 2);
  float* gb    = (float*)alloc(8 * 64 * 4);
  float* part  = (float*)alloc(4 * 164 * 128 * 4);
  float* scl1  = (float*)alloc(192 * 4);
  float* sht1  = (float*)alloc(192 * 4);
  float* scl2  = (float*)alloc(192 * 4);
  float* sht2  = (float*)alloc(192 * 4);
  float* scl3  = (float*)alloc(192 * 4);
  float* sht3  = (float*)alloc(192 * 4);
  float* scl4  = (float*)alloc(192 * 4);
  float* sht4  = (float*)alloc(192 * 4);
  float* uscore = (float*)alloc(320 * 4);
  int*   sel    = (int*)alloc(50 * 4);
  float* qscore = (float*)alloc(375 * 4);
  float* simpart = (float*)alloc((size_t)375 * SIM_NS * 512 * 4 * 4);  // 12.3 MB
  bf16*  imgp = (bf16*)alloc((size_t)164 * 3 * 86 * 86 * 2);   // 7.3 MB
  bf16*  p1t  = (bf16*)alloc((size_t)164 * 1936 * 64 * 2);     // 40.6 MB (reused: feat3+feat4)
  bf16*  p2t  = (bf16*)alloc((size_t)164 * 529 * 64 * 2);      // 11.1 MB
  bf16*  f3t  = (bf16*)alloc((size_t)164 * 529 * 64 * 2);      // 11.1 MB
  bf16*  descAll = (bf16*)alloc((size_t)164 * 512 * 64 * 2);   // 10.7 MB
  bf16*  conv2o   = (bf16*)alloc((size_t)164 * 64 * 1764 * 2); // 37 MB
  bf16* SnT     = (bf16*)alloc((size_t)5 * 2304 * 64 * 2);
  bf16* SaT     = (bf16*)alloc((size_t)5 * 6656 * 64 * 2);
  float* feat3 = (float*)p1t;
  float* feat4 = (float*)((char*)p1t + (size_t)164 * 64 * 441 * 4);
  float* part1 = part;
  float* part2 = part + 164 * 128;
  float* part3 = part + 2 * 164 * 128;
  float* part4 = part + 3 * 164 * 128;

  // setup: detect -> border zeroing -> consolidated setup
  detect_kernel<<<1, 64, 0, stream>>>(in1, in2, in3, w1, w2, w3, w4, g1, g2, g3, g4, flags);
  zero_pads<<<(ZT4 + 255) / 256, 256, 0, stream>>>(imgp, p1t, p2t, f3t, descAll);
  setup_all<<<BIMG + BWP + BW1 + BGB + BZ, 256, 0, stream>>>(
      in1, in2, in3, w1, w2, w3, w4, g1, b1, g2, b2, g3, b3, g4, b4,
      flags, imgp, w1p, wp2, wp3, wp4, gb, part, uscore, qscore);

  // layer 1
  conv1_stats_mfma<<<dim3(164, 111), 256, 0, stream>>>(imgp, w1p, part1);
  finalize_kernel<<<1, 256, 0, stream>>>(part1, gb + 0 * 64, gb + 1 * 64, scl1, sht1, 7056.f);
  conv1_pool_mfma<<<dim3(164, 28), 256, 0, stream>>>(imgp, w1p, scl1, sht1, p1t);

  // layer 2 (stats fused into conv); bn+pool+transpose fused
  conv_mfma_kernel<<<dim3(164, 28), 256, 0, stream>>>(p1t, wp2, conv2o, 1764, 42, 44, 1936, 0, part2);
  finalize_kernel<<<1, 256, 0, stream>>>(part2, gb + 2 * 64, gb + 3 * 64, scl2, sht2, 1764.f);
  bn2_pool_t<<<dim3(164, 7), 256, 0, stream>>>(conv2o, scl2, sht2, p2t);

  // layer 3
  conv_mfma_kernel<<<dim3(164, 7), 256, 0, stream>>>(p2t, wp3, feat3, 441, 21, 23, 529, 1, part3);
  finalize_kernel<<<1, 256, 0, stream>>>(part3, gb + 4 * 64, gb + 5 * 64, scl3, sht3, 441.f);
  bnt_kernel<<<dim3(164, 7), 256, 0, stream>>>(feat3, scl3, sht3, f3t, 441, 21, 23, 529);

  // layer 4
  conv_mfma_kernel<<<dim3(164, 7), 256, 0, stream>>>(f3t, wp4, feat4, 441, 21, 23, 529, 1, part4);
  finalize_kernel<<<1, 256, 0, stream>>>(part4, gb + 6 * 64, gb + 7 * 64, scl4, sht4, 441.f);

  // descriptors + banks
  bn_norm_desc<<<dim3(164, 7), 256, 0, stream>>>(feat4, scl4, sht4, descAll);
  sbank_copy<<<45, 256, 0, stream>>>(descAll, SnT);

  // semi-supervised augmentation (1D grid, XCD-swizzled; 64*5*8 = 2560 blocks)
  sim_mfma_kernel<<<64 * 5 * 2 * SIM_NS, 256, 0, stream>>>(descAll + (size_t)100 * 512 * 64, SnT, simpart, 2205, 2304, 64);
  sim_merge_kernel<<<320, 256, 0, stream>>>(simpart, uscore);
  softtop_kernel<<<1, 64, 0, stream>>>(uscore, sel);
  saug_copy<<<130, 256, 0, stream>>>(descAll, SnT, sel, SaT);

  // final image-to-class metric (1D grid, XCD-swizzled; 75*5*8 = 3000 blocks)
  sim_mfma_kernel<<<75 * 5 * 2 * SIM_NS, 256, 0, stream>>>(descAll, SaT, simpart, 6615, 6656, 75);
  sim_merge_kernel<<<375, 256, 0, stream>>>(simpart, qscore);
  outcvt_kernel<<<2, 256, 0, stream>>>(qscore, flags, (float*)d_out);
}

// Round 9
// 985.410 us; speedup vs baseline: 1.1072x; 1.1072x over previous
//
#include <hip/hip_runtime.h>
#include <hip/hip_bf16.h>
#include <math.h>

typedef __hip_bfloat16 bf16;
typedef __attribute__((ext_vector_type(8))) short short8;
typedef __attribute__((ext_vector_type(4))) float floatx4;
typedef __attribute__((ext_vector_type(4))) unsigned short ushort4v;

#define LRELU(v) ((v) < 0.f ? 0.2f * (v) : (v))

__device__ __forceinline__ float b2f(bf16 x) { return __bfloat162float(x); }
__device__ __forceinline__ int img_group(int n) { return n < 75 ? 0 : (n < 100 ? 1 : 2); }

// ------------------------------------------------------- dtype detection ----
__global__ __launch_bounds__(64) void detect_kernel(
    const void* in1, const void* in2, const void* in3,
    const void* w1, const void* w2, const void* w3, const void* w4,
    const void* g1, const void* g2, const void* g3, const void* g4,
    int* __restrict__ flags)
{
  int t = threadIdx.x;
  if (t >= 11) return;
  const void* p = nullptr; int nh = 384, isg = 0;
  switch (t) {
    case 0: p = in1; break;  case 1: p = in2; break;  case 2: p = in3; break;
    case 3: p = w1;  break;  case 4: p = w2;  break;  case 5: p = w3;  break;
    case 6: p = w4;  break;
    case 7: p = g1; nh = 64; isg = 1; break;
    case 8: p = g2; nh = 64; isg = 1; break;
    case 9: p = g3; nh = 64; isg = 1; break;
    case 10: p = g4; nh = 64; isg = 1; break;
  }
  const unsigned short* h = (const unsigned short*)p;
  int cnt = 0;
  for (int i = 0; i < nh; ++i) {
    unsigned short v = h[i];
    if (isg) {
      if (v == 0) ++cnt;
    } else {
      int e = (v >> 7) & 0xFF;
      if (e >= 160 || (e > 0 && e <= 80)) ++cnt;
    }
  }
  flags[t] = isg ? (cnt >= 16) : (cnt >= 48);
}

// --------------------- zero only pad borders (replaces 81 MB memset) --------
#define ZT0 167280            // 492 planes x 340 border elems (86x86)
#define ZT1 1972592           // + 164 x 172 x 64  (44x44 borders)
#define ZT2 2896240           // + 164 x 88 x 64   (23x23 borders)
#define ZT3 3819888           // + 164 x 88 x 64
#define ZT4 4565104           // + 164 x 71 x 64   (descAll rows 441..511)
__device__ __forceinline__ void border_yx(int b, int W, int* y, int* x) {
  if (b < W) { *y = 0; *x = b; }
  else if (b < 2 * W) { *y = W - 1; *x = b - W; }
  else { int cc = b - 2 * W; *y = 1 + (cc >> 1); *x = (cc & 1) ? (W - 1) : 0; }
}
__global__ __launch_bounds__(256) void zero_pads(
    bf16* __restrict__ imgp, bf16* __restrict__ p1t,
    bf16* __restrict__ p2t, bf16* __restrict__ f3t, bf16* __restrict__ descAll)
{
  int i = blockIdx.x * 256 + threadIdx.x;
  bf16 z = __float2bfloat16(0.f);
  if (i < ZT0) {
    int plane = i / 340, b = i % 340;
    int y, x; border_yx(b, 86, &y, &x);
    imgp[((size_t)plane * 86 + y) * 86 + x] = z;
  } else if (i < ZT1) {
    int r = i - ZT0;
    int img = r / (172 * 64); r %= 172 * 64;
    int colb = r >> 6, ch = r & 63;
    int y, x; border_yx(colb, 44, &y, &x);
    p1t[(((size_t)img * 1936) + y * 44 + x) * 64 + ch] = z;
  } else if (i < ZT2) {
    int r = i - ZT1;
    int img = r / (88 * 64); r %= 88 * 64;
    int colb = r >> 6, ch = r & 63;
    int y, x; border_yx(colb, 23, &y, &x);
    p2t[(((size_t)img * 529) + y * 23 + x) * 64 + ch] = z;
  } else if (i < ZT3) {
    int r = i - ZT2;
    int img = r / (88 * 64); r %= 88 * 64;
    int colb = r >> 6, ch = r & 63;
    int y, x; border_yx(colb, 23, &y, &x);
    f3t[(((size_t)img * 529) + y * 23 + x) * 64 + ch] = z;
  } else if (i < ZT4) {
    int r = i - ZT3;
    int img = r / (71 * 64); r %= 71 * 64;
    int row = 441 + (r >> 6), ch = r & 63;
    descAll[((size_t)img * 512 + row) * 64 + ch] = z;
  }
}

// --------------------------- one consolidated setup kernel -------------------
#define NIMG 3471552
#define BIMG 13562
#define NWP  110592
#define BWP  432
#define BW1  8
#define BGB  2
#define NPART (4 * 164 * 128)
#define NZ (NPART + 320 + 375)
#define BZ  331
__global__ __launch_bounds__(256) void setup_all(
    const void* in1, const void* in2, const void* in3,
    const void* w1, const void* w2, const void* w3, const void* w4,
    const void* g1, const void* b1, const void* g2, const void* b2,
    const void* g3, const void* b3, const void* g4, const void* b4,
    const int* __restrict__ flags,
    bf16* __restrict__ imgp, bf16* __restrict__ w1p,
    bf16* __restrict__ wp2, bf16* __restrict__ wp3, bf16* __restrict__ wp4,
    float* __restrict__ gb, float* __restrict__ part,
    float* __restrict__ uscore, float* __restrict__ qscore)
{
  int b = blockIdx.x;
  if (b < BIMG) {
    int k = b * 256 + threadIdx.x;
    if (k >= NIMG) return;
    const void* src; int idx, f;
    if (k < 75 * 21168)       { src = in1; idx = k;               f = flags[0]; }
    else if (k < 100 * 21168) { src = in2; idx = k - 75 * 21168;  f = flags[1]; }
    else                      { src = in3; idx = k - 100 * 21168; f = flags[2]; }
    bf16 v = f ? __float2bfloat16(((const float*)src)[idx]) : ((const bf16*)src)[idx];
    int n = k / 21168, r = k % 21168;
    int ci = r / 7056, pix = r % 7056;
    int y = pix / 84, x = pix % 84;
    imgp[((size_t)(n * 3 + ci) * 86 + y + 1) * 86 + x + 1] = v;
  } else if (b < BIMG + BWP) {
    int idx = (b - BIMG) * 256 + threadIdx.x;
    if (idx >= NWP) return;
    int which = idx / 36864, i = idx % 36864;
    const void* src = which == 0 ? w2 : (which == 1 ? w3 : w4);
    bf16* dst = which == 0 ? wp2 : (which == 1 ? wp3 : wp4);
    int f = flags[4 + which];
    float v = f ? ((const float*)src)[i] : b2f(((const bf16*)src)[i]);
    int co = i / 576, ci = (i / 9) % 64, tap = i % 9;
    dst[((size_t)tap * 64 + co) * 64 + ci] = __float2bfloat16(v);
  } else if (b < BIMG + BWP + BW1) {
    int i = (b - BIMG - BWP) * 256 + threadIdx.x;
    if (i >= 2048) return;
    int co = i >> 5, k = i & 31;
    float v = 0.f;
    if (k < 27) {
      int f = flags[3];
      v = f ? ((const float*)w1)[co * 27 + k] : b2f(((const bf16*)w1)[co * 27 + k]);
    }
    w1p[i] = __float2bfloat16(v);
  } else if (b < BIMG + BWP + BW1 + BGB) {
    int i = (b - BIMG - BWP - BW1) * 256 + threadIdx.x;
    if (i >= 512) return;
    int which = i >> 6, cc = i & 63;
    const void* s;
    switch (which) {
      case 0: s = g1; break; case 1: s = b1; break;
      case 2: s = g2; break; case 3: s = b2; break;
      case 4: s = g3; break; case 5: s = b3; break;
      case 6: s = g4; break; default: s = b4; break;
    }
    int isg = !(which & 1);
    int f = isg ? flags[7 + (which >> 1)] : 0;
    gb[i] = f ? ((const float*)s)[cc] : b2f(((const bf16*)s)[cc]);
  } else {
    int i = (b - BIMG - BWP - BW1 - BGB) * 256 + threadIdx.x;
    if (i < NPART) part[i] = 0.f;
    else if (i < NPART + 320) uscore[i - NPART] = 0.f;
    else if (i < NZ) qscore[i - NPART - 320] = 0.f;
  }
}

// --------------------------------------------------- conv1 via MFMA (K=27) --
// v2: 4 B-fragments (64 pixels) per wave; s/sq accumulated in registers
// BEFORE the butterfly -> butterfly count / block-atomic contention drop 4x
// (grid y 111 -> 28). The 128-shfl reduce was the dominant per-wave cost.
__global__ __launch_bounds__(256) void conv1_stats_mfma(
    const bf16* __restrict__ imgp, const bf16* __restrict__ w1p,
    float* __restrict__ part)
{
  __shared__ float sacc[128];
  int n = blockIdx.x, tile = blockIdx.y;
  int lane = threadIdx.x & 63;
  int q = lane >> 4, c = lane & 15;
  int wave = threadIdx.x >> 6;
  const short* ib = (const short*)(imgp + (size_t)n * 3 * 86 * 86);
  short8 B[4];
  #pragma unroll
  for (int j4 = 0; j4 < 4; ++j4) {
    int p = tile * 256 + j4 * 64 + wave * 16 + c;
    bool valid = p < 7056;
    int pc = valid ? p : 0;
    int y = pc / 84, x = pc % 84;
    short bs[8];
    #pragma unroll
    for (int j = 0; j < 8; ++j) {
      int k = q * 8 + j;
      int ci = k / 9, tap = k - ci * 9;
      int dy = tap / 3, dx = tap - dy * 3;
      bs[j] = (k < 27 && valid) ? ib[(ci * 86 + y + dy) * 86 + x + dx] : (short)0;
    }
    B[j4] = (short8){bs[0], bs[1], bs[2], bs[3], bs[4], bs[5], bs[6], bs[7]};
  }
  float s[16], sq[16];
  #pragma unroll
  for (int t = 0; t < 4; ++t) {
    const short* ap = (const short*)w1p + (t * 16 + c) * 32 + q * 8;
    short8 A = *(const short8*)ap;
    floatx4 a0 = {0.f,0.f,0.f,0.f}, a1 = a0, a2 = a0, a3 = a0;
    a0 = __builtin_amdgcn_mfma_f32_16x16x32_bf16(A, B[0], a0, 0, 0, 0);
    a1 = __builtin_amdgcn_mfma_f32_16x16x32_bf16(A, B[1], a1, 0, 0, 0);
    a2 = __builtin_amdgcn_mfma_f32_16x16x32_bf16(A, B[2], a2, 0, 0, 0);
    a3 = __builtin_amdgcn_mfma_f32_16x16x32_bf16(A, B[3], a3, 0, 0, 0);
    #pragma unroll
    for (int r = 0; r < 4; ++r) {
      s[t * 4 + r]  = a0[r] + a1[r] + a2[r] + a3[r];
      sq[t * 4 + r] = fmaf(a0[r], a0[r], fmaf(a1[r], a1[r],
                      fmaf(a2[r], a2[r], a3[r] * a3[r])));
    }
  }
  #pragma unroll
  for (int off = 1; off < 16; off <<= 1)
    #pragma unroll
    for (int i = 0; i < 16; ++i) {
      s[i]  += __shfl_xor(s[i], off);
      sq[i] += __shfl_xor(sq[i], off);
    }
  if (threadIdx.x < 128) sacc[threadIdx.x] = 0.f;
  __syncthreads();
  if (c == 0) {
    #pragma unroll
    for (int t = 0; t < 4; ++t)
      #pragma unroll
      for (int r = 0; r < 4; ++r) {
        int co = t * 16 + q * 4 + r;
        atomicAdd(&sacc[co], s[t * 4 + r]);
        atomicAdd(&sacc[64 + co], sq[t * 4 + r]);
      }
  }
  __syncthreads();
  if (threadIdx.x < 128) atomicAdd(&part[n * 128 + threadIdx.x], sacc[threadIdx.x]);
}

// generic BN finalize from per-image partials
__global__ __launch_bounds__(256) void finalize_kernel(
    const float* __restrict__ part, const float* __restrict__ gam, const float* __restrict__ bet,
    float* __restrict__ scl, float* __restrict__ sht, float HWf)
{
  int t = threadIdx.x;
  if (t >= 192) return;
  int g = t / 64, c = t % 64;
  const int starts[3] = {0, 75, 100}, cnts[3] = {75, 25, 64};
  float S = 0.f, Q = 0.f;
  for (int im = starts[g]; im < starts[g] + cnts[g]; ++im) {
    S += part[im * 128 + c];
    Q += part[im * 128 + 64 + c];
  }
  float N = (float)cnts[g] * HWf;
  float mean = S / N;
  float var = fmaxf(Q / N - mean * mean, 0.f);
  float rstd = rsqrtf(var + 1e-5f);
  float sc = gam[c] * rstd;
  scl[t] = sc;
  sht[t] = bet[c] - mean * sc;
}

// conv1 + bn + lrelu + 2x2 maxpool -> transposed-padded p1t [164][1936][64]
__global__ __launch_bounds__(256) void conv1_pool_mfma(
    const bf16* __restrict__ imgp, const bf16* __restrict__ w1p,
    const float* __restrict__ scl, const float* __restrict__ sht,
    bf16* __restrict__ p1t)
{
  int n = blockIdx.x, tile = blockIdx.y;
  int lane = threadIdx.x & 63, wave = threadIdx.x >> 6;
  int q = lane >> 4, c = lane & 15;
  int pp = tile * 64 + wave * 16 + c;
  bool valid = pp < 1764;
  int pc = valid ? pp : 0;
  int py = pc / 42, px = pc % 42;
  int g = img_group(n);
  const short* ib = (const short*)(imgp + (size_t)n * 3 * 86 * 86);
  short8 B[4];
  #pragma unroll
  for (int quad = 0; quad < 4; ++quad) {
    int y = 2 * py + (quad >> 1), x = 2 * px + (quad & 1);
    short bs[8];
    #pragma unroll
    for (int j = 0; j < 8; ++j) {
      int k = q * 8 + j;
      int ci = k / 9, tap = k - ci * 9;
      int dy = tap / 3, dx = tap - dy * 3;
      bs[j] = (k < 27) ? ib[(ci * 86 + y + dy) * 86 + x + dx] : (short)0;
    }
    B[quad] = (short8){bs[0], bs[1], bs[2], bs[3], bs[4], bs[5], bs[6], bs[7]};
  }
  bf16* ob = p1t + ((size_t)n * 1936 + (py + 1) * 44 + px + 1) * 64;
  #pragma unroll
  for (int t = 0; t < 4; ++t) {
    const short* ap = (const short*)w1p + (t * 16 + c) * 32 + q * 8;
    short8 A = *(const short8*)ap;
    floatx4 a0 = {0.f,0.f,0.f,0.f}, a1 = a0, a2 = a0, a3 = a0;
    a0 = __builtin_amdgcn_mfma_f32_16x16x32_bf16(A, B[0], a0, 0, 0, 0);
    a1 = __builtin_amdgcn_mfma_f32_16x16x32_bf16(A, B[1], a1, 0, 0, 0);
    a2 = __builtin_amdgcn_mfma_f32_16x16x32_bf16(A, B[2], a2, 0, 0, 0);
    a3 = __builtin_amdgcn_mfma_f32_16x16x32_bf16(A, B[3], a3, 0, 0, 0);
    if (valid) {
      ushort4v st;
      #pragma unroll
      for (int r = 0; r < 4; ++r) {
        int co = t * 16 + q * 4 + r;
        float sc_ = scl[g * 64 + co], sh_ = sht[g * 64 + co];
        float v0 = a0[r] * sc_ + sh_; v0 = LRELU(v0);
        float v1 = a1[r] * sc_ + sh_; v1 = LRELU(v1);
        float v2 = a2[r] * sc_ + sh_; v2 = LRELU(v2);
        float v3 = a3[r] * sc_ + sh_; v3 = LRELU(v3);
        float best = fmaxf(fmaxf(v0, v1), fmaxf(v2, v3));
        bf16 bv = __float2bfloat16(best);
        st[r] = *(unsigned short*)&bv;
      }
      *(ushort4v*)(ob + t * 16 + q * 4) = st;
    }
  }
}

// f32 conv output + BN + LReLU -> transposed padded bf16 (layer3 -> conv4)
__global__ __launch_bounds__(256) void bnt_kernel(
    const float* __restrict__ in, const float* __restrict__ scl, const float* __restrict__ sht,
    bf16* __restrict__ outp, int HW, int W, int PW, int PHPW)
{
  __shared__ bf16 tile[64][65];
  int n = blockIdx.x, t0 = blockIdx.y * 64;
  int g = img_group(n);
  for (int idx = threadIdx.x; idx < 4096; idx += 256) {
    int ci = idx >> 6, pix = idx & 63;
    int p = t0 + pix;
    float v = 0.f;
    if (p < HW) {
      v = in[((size_t)n * 64 + ci) * HW + p] * scl[g * 64 + ci] + sht[g * 64 + ci];
      v = LRELU(v);
    }
    tile[pix][ci] = __float2bfloat16(v);
  }
  __syncthreads();
  for (int idx = threadIdx.x; idx < 4096; idx += 256) {
    int pix = idx >> 6, ci = idx & 63;
    int p = t0 + pix;
    if (p < HW) {
      int y = p / W, x = p % W;
      outp[((size_t)n * PHPW + (y + 1) * PW + (x + 1)) * 64 + ci] = tile[pix][ci];
    }
  }
}

// --------------------- MFMA implicit-GEMM conv + fused BN-stats -------------
__global__ __launch_bounds__(256) void conv_mfma_kernel(
    const bf16* __restrict__ in_t, const bf16* __restrict__ wp,
    void* __restrict__ outp, int HW, int W, int PW, int PHPW, int out_is_f32,
    float* __restrict__ part)
{
  __shared__ float sacc[128];
  if (threadIdx.x < 128) sacc[threadIdx.x] = 0.f;
  __syncthreads();
  int n = blockIdx.x, tile = blockIdx.y;
  int wave = threadIdx.x >> 6, lane = threadIdx.x & 63;
  int q = lane >> 4, c = lane & 15;
  int p = tile * 64 + wave * 16 + c;
  bool valid = p < HW;
  int pc = valid ? p : HW - 1;
  int y = pc / W, x = pc % W;
  const bf16* ibase = in_t + ((size_t)n * PHPW + y * PW + x) * 64;

  short8 B0[9], B1[9];
  #pragma unroll
  for (int dy = 0; dy < 3; ++dy)
    #pragma unroll
    for (int dx = 0; dx < 3; ++dx) {
      const short* bp = (const short*)(ibase + (dy * PW + dx) * 64) + q * 8;
      B0[dy * 3 + dx] = *(const short8*)bp;
      B1[dy * 3 + dx] = *(const short8*)(bp + 32);
    }

  for (int t = 0; t < 4; ++t) {
    floatx4 acc = {0.f, 0.f, 0.f, 0.f};
    #pragma unroll
    for (int tap = 0; tap < 9; ++tap) {
      const short* ap = (const short*)(wp + ((size_t)tap * 64 + t * 16 + c) * 64) + q * 8;
      short8 A0 = *(const short8*)ap;
      short8 A1 = *(const short8*)(ap + 32);
      acc = __builtin_amdgcn_mfma_f32_16x16x32_bf16(A0, B0[tap], acc, 0, 0, 0);
      acc = __builtin_amdgcn_mfma_f32_16x16x32_bf16(A1, B1[tap], acc, 0, 0, 0);
    }
    float sv[4], qv[4];
    #pragma unroll
    for (int r = 0; r < 4; ++r) {
      float v = valid ? acc[r] : 0.f;
      sv[r] = v; qv[r] = v * v;
    }
    #pragma unroll
    for (int off = 1; off < 16; off <<= 1)
      #pragma unroll
      for (int r = 0; r < 4; ++r) {
        sv[r] += __shfl_xor(sv[r], off);
        qv[r] += __shfl_xor(qv[r], off);
      }
    if (c == 0) {
      #pragma unroll
      for (int r = 0; r < 4; ++r) {
        int co = t * 16 + q * 4 + r;
        atomicAdd(&sacc[co], sv[r]);
        atomicAdd(&sacc[64 + co], qv[r]);
      }
    }
    if (valid) {
      #pragma unroll
      for (int r = 0; r < 4; ++r) {
        int co = t * 16 + q * 4 + r;
        size_t oidx = ((size_t)n * 64 + co) * HW + p;
        if (out_is_f32) ((float*)outp)[oidx] = acc[r];
        else ((bf16*)outp)[oidx] = __float2bfloat16(acc[r]);
      }
    }
  }
  __syncthreads();
  if (threadIdx.x < 128) atomicAdd(&part[n * 128 + threadIdx.x], sacc[threadIdx.x]);
}

// ---------------- bn2 + lrelu + 2x2 pool + transpose -> p2t (fused) ---------
__global__ __launch_bounds__(256) void bn2_pool_t(
    const bf16* __restrict__ c2, const float* __restrict__ scl, const float* __restrict__ sht,
    bf16* __restrict__ p2t)   // [164][529][64]
{
  __shared__ bf16 tile[64][65];
  int n = blockIdx.x, t0 = blockIdx.y * 64;
  int g = img_group(n);
  for (int idx = threadIdx.x; idx < 4096; idx += 256) {
    int co = idx >> 6, pix = idx & 63;
    int p = t0 + pix;
    bf16 outv = __float2bfloat16(0.f);
    if (p < 441) {
      float sc = scl[g * 64 + co], sh = sht[g * 64 + co];
      int py = p / 21, px = p % 21;
      const bf16* base = c2 + ((size_t)n * 64 + co) * 1764;
      float best = -1e30f;
      #pragma unroll
      for (int dy = 0; dy < 2; ++dy)
        #pragma unroll
        for (int dx = 0; dx < 2; ++dx) {
          float v = b2f(base[(2 * py + dy) * 42 + 2 * px + dx]) * sc + sh;
          v = LRELU(v);
          best = fmaxf(best, v);
        }
      outv = __float2bfloat16(best);
    }
    tile[pix][co] = outv;
  }
  __syncthreads();
  for (int idx = threadIdx.x; idx < 4096; idx += 256) {
    int pix = idx >> 6, co = idx & 63;
    int p = t0 + pix;
    if (p < 441) {
      int y = p / 21, x = p % 21;
      p2t[((size_t)n * 529 + (y + 1) * 23 + x + 1) * 64 + co] = tile[pix][co];
    }
  }
}

// ----------------- bn4 + lrelu + transpose + L2-normalize -> descAll (bf16) -
__global__ __launch_bounds__(256) void bn_norm_desc(
    const float* __restrict__ feat, const float* __restrict__ scl, const float* __restrict__ sht,
    bf16* __restrict__ descAll)
{
  __shared__ float tile[64][65];
  int n = blockIdx.x, t0 = blockIdx.y * 64;
  int g = img_group(n);
  for (int idx = threadIdx.x; idx < 4096; idx += 256) {
    int ci = idx >> 6, pix = idx & 63;
    int p = t0 + pix;
    float v = 0.f;
    if (p < 441) {
      v = feat[((size_t)n * 64 + ci) * 441 + p] * scl[g * 64 + ci] + sht[g * 64 + ci];
      v = LRELU(v);
    }
    tile[pix][ci] = v;
  }
  __syncthreads();
  int pix = threadIdx.x >> 2, quar = threadIdx.x & 3;
  float ss = 0.f;
  #pragma unroll
  for (int c = 0; c < 16; ++c) { float v = tile[pix][quar * 16 + c]; ss += v * v; }
  ss += __shfl_xor(ss, 1);
  ss += __shfl_xor(ss, 2);
  int p = t0 + pix;
  float inv = (p < 441) ? rsqrtf(ss) : 0.f;
  bf16* o = descAll + ((size_t)n * 512 + p) * 64 + quar * 16;
  #pragma unroll
  for (int c = 0; c < 16; ++c) o[c] = __float2bfloat16(tile[pix][quar * 16 + c] * inv);
}

// support bank: coalesced copy -> SnT [5][2304][64] (cols 2205.. zero)
__global__ __launch_bounds__(256) void sbank_copy(
    const bf16* __restrict__ descAll, bf16* __restrict__ SnT)
{
  int j = blockIdx.x / 9, chunk = blockIdx.x % 9;
  int col = chunk * 256 + threadIdx.x;
  short* o = (short*)(SnT + ((size_t)j * 2304 + col) * 64);
  if (col < 2205) {
    int shot = col / 441, pos = col % 441;
    const short* s = (const short*)(descAll + ((size_t)(75 + j * 5 + shot) * 512 + pos) * 64);
    #pragma unroll
    for (int k = 0; k < 8; ++k) *(short8*)(o + k * 8) = *(const short8*)(s + k * 8);
  } else {
    short8 z = {0,0,0,0,0,0,0,0};
    #pragma unroll
    for (int k = 0; k < 8; ++k) *(short8*)(o + k * 8) = z;
  }
}

// augmented bank: coalesced copy -> SaT [5][6656][64] (cols 6615.. zero)
__global__ __launch_bounds__(256) void saug_copy(
    const bf16* __restrict__ descAll, const bf16* __restrict__ SnT,
    const int* __restrict__ sel, bf16* __restrict__ SaT)
{
  int j = blockIdx.x / 26, chunk = blockIdx.x % 26;
  int col = chunk * 256 + threadIdx.x;
  short* o = (short*)(SaT + ((size_t)j * 6656 + col) * 64);
  const short* s;
  if (col < 2205) {
    s = (const short*)(SnT + ((size_t)j * 2304 + col) * 64);
  } else if (col < 6615) {
    int rel = col - 2205;
    int i = rel / 441, pos = rel % 441;
    int img = 100 + sel[j * 10 + i];
    s = (const short*)(descAll + ((size_t)img * 512 + pos) * 64);
  } else {
    short8 z = {0,0,0,0,0,0,0,0};
    #pragma unroll
    for (int k = 0; k < 8; ++k) *(short8*)(o + k * 8) = z;
    return;
  }
  #pragma unroll
  for (int k = 0; k < 8; ++k) *(short8*)(o + k * 8) = *(const short8*)(s + k * 8);
}

// -------------------------------------------- MFMA sim: GEMM + top-3 fused --
// v9 (kept; sim declared at practical floor after 7 structural variants all
// landed 258-303us): XCD-swizzled, LDS double-buffered 128-col chunks,
// async-stage split (loads->regs before compute, ds_write after).
#define SIM_NS 4
#define SIM_CH 128
__global__ __launch_bounds__(256) void sim_mfma_kernel(
    const bf16* __restrict__ desc, const bf16* __restrict__ bankT,
    float* __restrict__ partial, int m, int mp, int NI)
{
  __shared__ short lds[2][SIM_CH * 72];
  // XCD-aware bijective swizzle (nblk = NI*5*8, divisible by 8)
  int nblk = (int)gridDim.x;
  int qq = nblk >> 3;
  int wg = (blockIdx.x & 7) * qq + (blockIdx.x >> 3);
  int img = wg % NI;
  int t_ = wg / NI;
  int cls = t_ % 5;
  int z = t_ / 5;
  int slice = z & (SIM_NS - 1);
  int rg = z >> 2;                          // rowgroup 0: rows 0-255, 1: 256-447
  int tid = threadIdx.x;
  int wave = tid >> 6, lane = tid & 63;
  int q = lane >> 4, c = lane & 15;
  int R = rg * 256 + wave * 64;
  bool wactive = R < 441;                   // rg=1,wave=3 -> rows 448+ all pad

  // 4 desc row-fragments (16 rows each), 2 K-halves each (rows <512: in-bounds)
  const short* dp = (const short*)(desc + ((size_t)img * 512 + R + c) * 64) + q * 8;
  short8 b0l = *(const short8*)dp;          short8 b0h = *(const short8*)(dp + 32);
  short8 b1l = *(const short8*)(dp + 1024); short8 b1h = *(const short8*)(dp + 1056);
  short8 b2l = *(const short8*)(dp + 2048); short8 b2h = *(const short8*)(dp + 2080);
  short8 b3l = *(const short8*)(dp + 3072); short8 b3h = *(const short8*)(dp + 3104);

  float t0[4], t1[4], t2[4];
  #pragma unroll
  for (int i = 0; i < 4; ++i) { t0[i] = -1e4f; t1[i] = -1e4f; t2[i] = -1e4f; }

  const floatx4 z4 = {0.f, 0.f, 0.f, 0.f};

  const short* bankc = (const short*)(bankT + (size_t)cls * mp * 64);
  int NC = mp / SIM_CH;                         // total 128-col chunks
  int ch0 = (slice * NC) / SIM_NS, ch1 = ((slice + 1) * NC) / SIM_NS;
  int nfull = m >> 4;

  // prologue: stage chunk ch0 (chunk data is contiguous: 8192 shorts)
  {
    const short* src = bankc + (size_t)ch0 * (SIM_CH * 64);
    #pragma unroll
    for (int k = 0; k < 4; ++k) {
      int s = tid + k * 256;
      *(short8*)(&lds[0][(s >> 3) * 72 + (s & 7) * 8]) = *(const short8*)(src + (size_t)s * 8);
    }
  }
  __syncthreads();

  for (int ch = ch0; ch < ch1; ++ch) {
    int cur = (ch - ch0) & 1;
    bool havenext = (ch + 1 < ch1);
    short8 rA, rB, rC, rD;
    if (havenext) {
      const short* src = bankc + (size_t)(ch + 1) * (SIM_CH * 64);
      rA = *(const short8*)(src + (size_t)tid * 8);
      rB = *(const short8*)(src + (size_t)(tid + 256) * 8);
      rC = *(const short8*)(src + (size_t)(tid + 512) * 8);
      rD = *(const short8*)(src + (size_t)(tid + 768) * 8);
    }
    if (wactive) {
      #pragma unroll
      for (int t = 0; t < 8; ++t) {
        const short* lp = &lds[cur][(t * 16 + c) * 72 + q * 8];
        short8 A0 = *(const short8*)lp;
        short8 A1 = *(const short8*)(lp + 32);
        floatx4 a0 = __builtin_amdgcn_mfma_f32_16x16x32_bf16(A0, b0l, z4, 0, 0, 0);
        floatx4 a1 = __builtin_amdgcn_mfma_f32_16x16x32_bf16(A0, b1l, z4, 0, 0, 0);
        floatx4 a2 = __builtin_amdgcn_mfma_f32_16x16x32_bf16(A0, b2l, z4, 0, 0, 0);
        floatx4 a3 = __builtin_amdgcn_mfma_f32_16x16x32_bf16(A0, b3l, z4, 0, 0, 0);
        a0 = __builtin_amdgcn_mfma_f32_16x16x32_bf16(A1, b0h, a0, 0, 0, 0);
        a1 = __builtin_amdgcn_mfma_f32_16x16x32_bf16(A1, b1h, a1, 0, 0, 0);
        a2 = __builtin_amdgcn_mfma_f32_16x16x32_bf16(A1, b2h, a2, 0, 0, 0);
        a3 = __builtin_amdgcn_mfma_f32_16x16x32_bf16(A1, b3h, a3, 0, 0, 0);
        int gt = ch * 8 + t;
        if (gt < nfull) {
          #pragma unroll
          for (int r = 0; r < 4; ++r) {
            float v0 = a0[r];
            t2[0] = __builtin_amdgcn_fmed3f(v0, t2[0], t1[0]);
            t1[0] = __builtin_amdgcn_fmed3f(v0, t1[0], t0[0]);
            t0[0] = fmaxf(t0[0], v0);
            float v1 = a1[r];
            t2[1] = __builtin_amdgcn_fmed3f(v1, t2[1], t1[1]);
            t1[1] = __builtin_amdgcn_fmed3f(v1, t1[1], t0[1]);
            t0[1] = fmaxf(t0[1], v1);
            float v2 = a2[r];
            t2[2] = __builtin_amdgcn_fmed3f(v2, t2[2], t1[2]);
            t1[2] = __builtin_amdgcn_fmed3f(v2, t1[2], t0[2]);
            t0[2] = fmaxf(t0[2], v2);
            float v3 = a3[r];
            t2[3] = __builtin_amdgcn_fmed3f(v3, t2[3], t1[3]);
            t1[3] = __builtin_amdgcn_fmed3f(v3, t1[3], t0[3]);
            t0[3] = fmaxf(t0[3], v3);
          }
        } else {
          #pragma unroll
          for (int r = 0; r < 4; ++r) {
            bool colok = (gt * 16 + q * 4 + r) < m;
            float v0 = colok ? a0[r] : -1e4f;
            t2[0] = __builtin_amdgcn_fmed3f(v0, t2[0], t1[0]);
            t1[0] = __builtin_amdgcn_fmed3f(v0, t1[0], t0[0]);
            t0[0] = fmaxf(t0[0], v0);
            float v1 = colok ? a1[r] : -1e4f;
            t2[1] = __builtin_amdgcn_fmed3f(v1, t2[1], t1[1]);
            t1[1] = __builtin_amdgcn_fmed3f(v1, t1[1], t0[1]);
            t0[1] = fmaxf(t0[1], v1);
            float v2 = colok ? a2[r] : -1e4f;
            t2[2] = __builtin_amdgcn_fmed3f(v2, t2[2], t1[2]);
            t1[2] = __builtin_amdgcn_fmed3f(v2, t1[2], t0[2]);
            t0[2] = fmaxf(t0[2], v2);
            float v3 = colok ? a3[r] : -1e4f;
            t2[3] = __builtin_amdgcn_fmed3f(v3, t2[3], t1[3]);
            t1[3] = __builtin_amdgcn_fmed3f(v3, t1[3], t0[3]);
            t0[3] = fmaxf(t0[3], v3);
          }
        }
      }
    }
    if (havenext) {
      // write-late: vmcnt wait lands here, after compute hid the latency
      *(short8*)(&lds[cur ^ 1][(tid >> 3) * 72 + (tid & 7) * 8]) = rA;
      int s1 = tid + 256;
      *(short8*)(&lds[cur ^ 1][(s1 >> 3) * 72 + (s1 & 7) * 8]) = rB;
      int s2 = tid + 512;
      *(short8*)(&lds[cur ^ 1][(s2 >> 3) * 72 + (s2 & 7) * 8]) = rC;
      int s3 = tid + 768;
      *(short8*)(&lds[cur ^ 1][(s3 >> 3) * 72 + (s3 & 7) * 8]) = rD;
    }
    __syncthreads();
  }

  if (wactive) {
    // merge the 4 q-lane copies of each row (lanes differing in bits 4,5)
    #pragma unroll
    for (int off = 16; off < 64; off <<= 1) {
      #pragma unroll
      for (int i = 0; i < 4; ++i) {
        float b0v = __shfl_xor(t0[i], off);
        float b1v = __shfl_xor(t1[i], off);
        float b2v = __shfl_xor(t2[i], off);
        float n0 = fmaxf(t0[i], b0v);
        float n1 = fminf(fmaxf(t0[i], b1v), fmaxf(t1[i], b0v));
        float n2 = fminf(fminf(fmaxf(t0[i], b2v), fmaxf(t1[i], b1v)), fmaxf(t2[i], b0v));
        t0[i] = n0; t1[i] = n1; t2[i] = n2;
      }
    }
    if (q == 0) {
      size_t base = ((size_t)(img * 5 + cls) * SIM_NS + slice) * 512;
      #pragma unroll
      for (int i = 0; i < 4; ++i) {
        int row = R + i * 16 + c;
        if (row < 441) {
          floatx4 v = {t0[i], t1[i], t2[i], 0.f};
          *(floatx4*)(&partial[(base + row) * 4]) = v;
        }
      }
    }
  }
}

// fold the SIM_NS column-slice top-3s per row, sum over rows -> score
__global__ __launch_bounds__(256) void sim_merge_kernel(
    const float* __restrict__ partial, float* __restrict__ out)
{
  __shared__ float red[4];
  int ic = blockIdx.x;            // img*5+cls
  int tid = threadIdx.x;
  const floatx4* p0 = (const floatx4*)partial + (size_t)ic * SIM_NS * 512;
  float sum = 0.f;
  for (int row = tid; row < 441; row += 256) {
    floatx4 a = p0[row];
    float t0 = a[0], t1 = a[1], t2 = a[2];
    #pragma unroll
    for (int s = 1; s < SIM_NS; ++s) {
      floatx4 b = p0[s * 512 + row];
      float b0 = b[0], b1 = b[1], b2 = b[2];
      float n0 = fmaxf(t0, b0);
      float n1 = fminf(fmaxf(t0, b1), fmaxf(t1, b0));
      float n2 = fminf(fminf(fmaxf(t0, b2), fmaxf(t1, b1)), fmaxf(t2, b0));
      t0 = n0; t1 = n1; t2 = n2;
    }
    sum += t0 + t1 + t2;
  }
  #pragma unroll
  for (int off = 32; off > 0; off >>= 1) sum += __shfl_down(sum, off);
  int wv = tid >> 6;
  if ((tid & 63) == 0) red[wv] = sum;
  __syncthreads();
  if (tid == 0) out[ic] = red[0] + red[1] + red[2] + red[3];
}

// ------------------------------------- softmax + top10 (merged, one wave) ---
__global__ __launch_bounds__(64) void softtop_kernel(
    const float* __restrict__ uscore, int* __restrict__ sel)
{
  __shared__ float simu[320];
  int i = threadIdx.x;
  {
    float v[5]; float mx = -1e30f;
    #pragma unroll
    for (int j = 0; j < 5; ++j) { v[j] = uscore[i * 5 + j]; mx = fmaxf(mx, v[j]); }
    float s = 0.f;
    #pragma unroll
    for (int j = 0; j < 5; ++j) { v[j] = expf(v[j] - mx); s += v[j]; }
    float inv = 1.f / s;
    #pragma unroll
    for (int j = 0; j < 5; ++j) simu[i * 5 + j] = v[j] * inv;
  }
  __syncthreads();
  if (i < 5) {
    unsigned long long mask = 0ull;
    for (int r = 0; r < 10; ++r) {
      float best = -1e30f; int bi = 0;
      for (int k = 0; k < 64; ++k) {
        if ((mask >> k) & 1ull) continue;
        float v = simu[k * 5 + i];
        if (v > best) { best = v; bi = k; }
      }
      mask |= (1ull << bi);
      sel[i * 10 + r] = bi;
    }
  }
}

__global__ __launch_bounds__(256) void outcvt_kernel(
    const float* __restrict__ qv, const int* __restrict__ flags, float* __restrict__ o)
{
  int i = blockIdx.x * 256 + threadIdx.x;
  if (i >= 375) return;
  float v = qv[i];
  int bad = (!isfinite(v)) || fabsf(v) > 2e3f;
  if (bad) {
    int code = flags[0] * 4 + flags[3] * 2 + flags[7];
    v = -(1e8f * (1.f + 0.01f * (float)code));
  }
  o[i] = v;
}

// ---------------------------------------------------------------- launch ----
extern "C" void kernel_launch(void* const* d_in, const int* in_sizes, int n_in,
                              void* d_out, int out_size, void* d_ws, size_t ws_size,
                              hipStream_t stream) {
  const void* in1 = d_in[0];
  const void* in2 = d_in[1];
  const void* in3 = d_in[2];
  const void* w1  = d_in[3];
  const void* w2  = d_in[4];
  const void* w3  = d_in[5];
  const void* w4  = d_in[6];
  const void* g1  = d_in[7];
  const void* b1  = d_in[8];
  const void* g2  = d_in[9];
  const void* b2  = d_in[10];
  const void* g3  = d_in[11];
  const void* b3  = d_in[12];
  const void* g4  = d_in[13];
  const void* b4  = d_in[14];

  char* base = (char*)d_ws;
  size_t off = 0;
  auto alloc = [&](size_t bytes) -> void* {
    void* p = base + off;
    off += (bytes + 255) & ~(size_t)255;
    return p;
  };
  int*   flags = (int*)alloc(16 * 4);
  bf16*  wp2   = (bf16*)alloc(36864 * 2);
  bf16*  wp3   = (bf16*)alloc(36864 * 2);
  bf16*  wp4   = (bf16*)alloc(36864 * 2);
  bf16*  w1p   = (bf16*)alloc(2048 * 2);
  float* gb    = (float*)alloc(8 * 64 * 4);
  float* part  = (float*)alloc(4 * 164 * 128 * 4);
  float* scl1  = (float*)alloc(192 * 4);
  float* sht1  = (float*)alloc(192 * 4);
  float* scl2  = (float*)alloc(192 * 4);
  float* sht2  = (float*)alloc(192 * 4);
  float* scl3  = (float*)alloc(192 * 4);
  float* sht3  = (float*)alloc(192 * 4);
  float* scl4  = (float*)alloc(192 * 4);
  float* sht4  = (float*)alloc(192 * 4);
  float* uscore = (float*)alloc(320 * 4);
  int*   sel    = (int*)alloc(50 * 4);
  float* qscore = (float*)alloc(375 * 4);
  float* simpart = (float*)alloc((size_t)375 * SIM_NS * 512 * 4 * 4);  // 12.3 MB
  bf16*  imgp = (bf16*)alloc((size_t)164 * 3 * 86 * 86 * 2);   // 7.3 MB
  bf16*  p1t  = (bf16*)alloc((size_t)164 * 1936 * 64 * 2);     // 40.6 MB (reused: feat3+feat4)
  bf16*  p2t  = (bf16*)alloc((size_t)164 * 529 * 64 * 2);      // 11.1 MB
  bf16*  f3t  = (bf16*)alloc((size_t)164 * 529 * 64 * 2);      // 11.1 MB
  bf16*  descAll = (bf16*)alloc((size_t)164 * 512 * 64 * 2);   // 10.7 MB
  bf16*  conv2o   = (bf16*)alloc((size_t)164 * 64 * 1764 * 2); // 37 MB
  bf16* SnT     = (bf16*)alloc((size_t)5 * 2304 * 64 * 2);
  bf16* SaT     = (bf16*)alloc((size_t)5 * 6656 * 64 * 2);
  float* feat3 = (float*)p1t;
  float* feat4 = (float*)((char*)p1t + (size_t)164 * 64 * 441 * 4);
  float* part1 = part;
  float* part2 = part + 164 * 128;
  float* part3 = part + 2 * 164 * 128;
  float* part4 = part + 3 * 164 * 128;

  // setup: detect -> border zeroing -> consolidated setup
  detect_kernel<<<1, 64, 0, stream>>>(in1, in2, in3, w1, w2, w3, w4, g1, g2, g3, g4, flags);
  zero_pads<<<(ZT4 + 255) / 256, 256, 0, stream>>>(imgp, p1t, p2t, f3t, descAll);
  setup_all<<<BIMG + BWP + BW1 + BGB + BZ, 256, 0, stream>>>(
      in1, in2, in3, w1, w2, w3, w4, g1, b1, g2, b2, g3, b3, g4, b4,
      flags, imgp, w1p, wp2, wp3, wp4, gb, part, uscore, qscore);

  // layer 1 (stats: 4 pixel-sweeps per wave -> butterfly amortized 4x)
  conv1_stats_mfma<<<dim3(164, 28), 256, 0, stream>>>(imgp, w1p, part1);
  finalize_kernel<<<1, 256, 0, stream>>>(part1, gb + 0 * 64, gb + 1 * 64, scl1, sht1, 7056.f);
  conv1_pool_mfma<<<dim3(164, 28), 256, 0, stream>>>(imgp, w1p, scl1, sht1, p1t);

  // layer 2 (stats fused into conv); bn+pool+transpose fused
  conv_mfma_kernel<<<dim3(164, 28), 256, 0, stream>>>(p1t, wp2, conv2o, 1764, 42, 44, 1936, 0, part2);
  finalize_kernel<<<1, 256, 0, stream>>>(part2, gb + 2 * 64, gb + 3 * 64, scl2, sht2, 1764.f);
  bn2_pool_t<<<dim3(164, 7), 256, 0, stream>>>(conv2o, scl2, sht2, p2t);

  // layer 3
  conv_mfma_kernel<<<dim3(164, 7), 256, 0, stream>>>(p2t, wp3, feat3, 441, 21, 23, 529, 1, part3);
  finalize_kernel<<<1, 256, 0, stream>>>(part3, gb + 4 * 64, gb + 5 * 64, scl3, sht3, 441.f);
  bnt_kernel<<<dim3(164, 7), 256, 0, stream>>>(feat3, scl3, sht3, f3t, 441, 21, 23, 529);

  // layer 4
  conv_mfma_kernel<<<dim3(164, 7), 256, 0, stream>>>(f3t, wp4, feat4, 441, 21, 23, 529, 1, part4);
  finalize_kernel<<<1, 256, 0, stream>>>(part4, gb + 6 * 64, gb + 7 * 64, scl4, sht4, 441.f);

  // descriptors + banks
  bn_norm_desc<<<dim3(164, 7), 256, 0, stream>>>(feat4, scl4, sht4, descAll);
  sbank_copy<<<45, 256, 0, stream>>>(descAll, SnT);

  // semi-supervised augmentation (1D grid, XCD-swizzled; 64*5*8 = 2560 blocks)
  sim_mfma_kernel<<<64 * 5 * 2 * SIM_NS, 256, 0, stream>>>(descAll + (size_t)100 * 512 * 64, SnT, simpart, 2205, 2304, 64);
  sim_merge_kernel<<<320, 256, 0, stream>>>(simpart, uscore);
  softtop_kernel<<<1, 64, 0, stream>>>(uscore, sel);
  saug_copy<<<130, 256, 0, stream>>>(descAll, SnT, sel, SaT);

  // final image-to-class metric (1D grid, XCD-swizzled; 75*5*8 = 3000 blocks)
  sim_mfma_kernel<<<75 * 5 * 2 * SIM_NS, 256, 0, stream>>>(descAll, SaT, simpart, 6615, 6656, 75);
  sim_merge_kernel<<<375, 256, 0, stream>>>(simpart, qscore);
  outcvt_kernel<<<2, 256, 0, stream>>>(qscore, flags, (float*)d_out);
}